// Round 9
// baseline (1960.296 us; speedup 1.0000x reference)
//
#include <hip/hip_runtime.h>
#include <stdint.h>
#include <stddef.h>

// ---------------------------------------------------------------------------
// Swin block, MI355X. bf16 MFMA GEMMs + fused window attention.
// B=64, HW=56, DIM=384, HEADS=12, HEAD_DIM=32, MLP=1536, WS=7, shift=3
// Round 9: depth-2 pipeline (R6 schedule, proven) x 4-waves/SIMD occupancy
// (R8 lever). 256x128 tile, 512 threads, 8 waves (4Mx2N), BK=32, 3 LDS
// buffers (72KB), counted vmcnt(3), one barrier per K-step.
// ---------------------------------------------------------------------------

typedef unsigned short u16;
typedef __attribute__((ext_vector_type(8))) short bf16x8;
typedef __attribute__((ext_vector_type(8))) unsigned short u16x8;
typedef __attribute__((ext_vector_type(4))) float f32x4;
typedef __attribute__((ext_vector_type(2))) float f32x2;

#define HW2 3136   // 56*56

__device__ __forceinline__ u16 f2bf(float f) {
    unsigned u = __float_as_uint(f);
    return (u16)((u + 0x7FFFu + ((u >> 16) & 1u)) >> 16);
}

__device__ __forceinline__ f32x4 mfma16(bf16x8 a, bf16x8 b, f32x4 c) {
    return __builtin_amdgcn_mfma_f32_16x16x32_bf16(a, b, c, 0, 0, 0);
}

__device__ __forceinline__ void a_copy16(const void* g, void* l) {
    __builtin_amdgcn_global_load_lds((const __attribute__((address_space(1))) void*)g,
                                     (__attribute__((address_space(3))) void*)l, 16, 0, 0);
}

// ---------------------------------------------------------------------------
// Weight transpose + bf16 convert: w[K][N] -> wt[N][K]
// ---------------------------------------------------------------------------
__global__ __launch_bounds__(256) void wtrans(const float* __restrict__ w,
                                              u16* __restrict__ wt, int K, int N) {
    long tid = (long)blockIdx.x * 256 + threadIdx.x;
    if (tid >= (long)K * N) return;
    int n = (int)(tid / K), k = (int)(tid % K);
    wt[tid] = f2bf(w[(long)k * N + n]);
}

// ---------------------------------------------------------------------------
// bias tables: tab[4][49][49] = pos_emb[rel] (+ul mask)(+lr mask)
// ---------------------------------------------------------------------------
__global__ __launch_bounds__(256) void prep_tab(const float* __restrict__ pe,
                                                float* __restrict__ tab) {
    int tid = blockIdx.x * 256 + threadIdx.x;
    if (tid >= 4 * 2401) return;
    int cb = tid / 2401, rem = tid % 2401;
    int i = rem / 49, j = rem % 49;
    int ix = i % 7, jx = j % 7;
    int iy = i / 7, jy = j / 7;
    float v = pe[(jy - iy + 6) * 13 + (jx - ix + 6)];
    if ((cb & 1) && ((i >= 28) != (j >= 28))) v += -1e9f;  // ul (bottom window row)
    if ((cb & 2) && ((ix >= 4) != (jx >= 4))) v += -1e9f;  // lr (right window col)
    tab[tid] = v;
}

// ---------------------------------------------------------------------------
// LayerNorm over 384, one wave per token (rows chunk-local). SHIFT=1: write
// rows in cyclically shifted order so attention sees contiguous windows.
// ---------------------------------------------------------------------------
template <int SHIFT>
__global__ __launch_bounds__(256) void ln_kernel(const float* __restrict__ in,
                                                 u16* __restrict__ out,
                                                 const float* __restrict__ gw,
                                                 const float* __restrict__ bw) {
    const int lane = threadIdx.x & 63;
    const int wave = threadIdx.x >> 6;
    const long t = (long)blockIdx.x * 4 + wave;
    const float* row = in + t * 384;
    f32x2 v0 = *(const f32x2*)(row + lane * 2);
    f32x2 v1 = *(const f32x2*)(row + 128 + lane * 2);
    f32x2 v2 = *(const f32x2*)(row + 256 + lane * 2);
    float s = v0.x + v0.y + v1.x + v1.y + v2.x + v2.y;
    float q = v0.x * v0.x + v0.y * v0.y + v1.x * v1.x + v1.y * v1.y + v2.x * v2.x + v2.y * v2.y;
#pragma unroll
    for (int m = 1; m < 64; m <<= 1) {
        s += __shfl_xor(s, m);
        q += __shfl_xor(q, m);
    }
    const float mean = s * (1.f / 384.f);
    const float rstd = rsqrtf(q * (1.f / 384.f) - mean * mean + 1e-5f);
    long orow = t;
    if (SHIFT) {
        long b = t / HW2;
        int rem = (int)(t % HW2);
        int y = rem / 56 - 3; if (y < 0) y += 56;
        int x = rem % 56 - 3; if (x < 0) x += 56;
        orow = b * HW2 + y * 56 + x;
    }
    u16* po = out + orow * 384;
#pragma unroll
    for (int p = 0; p < 3; p++) {
        f32x2 vv = (p == 0) ? v0 : ((p == 1) ? v1 : v2);
        f32x2 gg = *(const f32x2*)(gw + p * 128 + lane * 2);
        f32x2 bb = *(const f32x2*)(bw + p * 128 + lane * 2);
        float a0 = (vv.x - mean) * rstd * gg.x + bb.x;
        float a1 = (vv.y - mean) * rstd * gg.y + bb.y;
        unsigned pk = (unsigned)f2bf(a0) | ((unsigned)f2bf(a1) << 16);
        *(unsigned*)(po + p * 128 + lane * 2) = pk;
    }
}

// ---------------------------------------------------------------------------
// bf16 GEMM: 256x128 tile, BK=32, 512 threads, 8 waves (4Mx2N), each wave
// 64x64 out (acc 4x4 f32x4 = 64 AGPR). Depth-2 prefetch: 3 LDS buffer sets
// (A 16KB + B 8KB each, 72KB total); per K-step:
//   vmcnt(3) [tile t landed, t+1 in flight] -> s_barrier -> issue t+2
//   (3 loads/thread) -> ds_read tile t -> 16 MFMA.
// LDS dest linear (global_load_lds), source pre-swizzled; reads use the same
// XOR (slot ^= (row>>1)&3) -> conflict-free (verified 0 in R5-R8).
// __launch_bounds__(512,4): cap 128 unified regs -> 4 waves/SIMD with
// 2 blocks/CU (144KB LDS).
// A[M][K], Bt[N][K]. EPI: 0=bf16 store; 1=proj(+bias+resid, un-shift, f32);
// 2=+bias fast-GELU bf16; 3=+bias+resid f32.
// Requires (K/32) % 3 == 0 (K=384 or 1536 here), M % 256 == 0.
// Grids XCD-swizzled when gridDim%8==0.
// ---------------------------------------------------------------------------
template <int EPI>
__global__ __launch_bounds__(512, 4) void gemm_bf16(const u16* __restrict__ A,
                                                    const u16* __restrict__ Bt,
                                                    int N, int K,
                                                    const float* __restrict__ bias,
                                                    const float* resid,
                                                    float* outf, u16* outb) {
    __shared__ u16 Abuf[3][8192];   // 3 x [256 rows x 32 cols]
    __shared__ u16 Bbuf[3][4096];   // 3 x [128 rows x 32 cols]
    int bid = blockIdx.x;
    if ((gridDim.x & 7) == 0) {     // XCD-aware swizzle (bijective, %8==0)
        const int cpx = gridDim.x >> 3;
        bid = (bid & 7) * cpx + (bid >> 3);
    }
    const int ntiles = N >> 7;
    const long m0 = (long)(bid / ntiles) << 8;   // 256-row tiles
    const int n0 = (bid % ntiles) << 7;
    const int tid = threadIdx.x;
    const int lane = tid & 63;
    const int wave = tid >> 6;      // 0..7
    const int wr = (wave >> 1) << 6;  // 0,64,128,192
    const int wc = (wave & 1) << 6;   // 0,64
    const int lr = lane & 15;
    const int g  = lane >> 4;

    // staging: A 2 loads/thread (16KB), B 1 load/thread (8KB)
    const u16 *aP0, *aP1, *bP0;
    int d0, d1, db;
    {
        const int o0 = tid * 16;                          // [0,8192)
        const int r0 = o0 >> 6;                           // 0..127
        const int c0 = (((o0 >> 4) & 3) ^ ((r0 >> 1) & 3)) << 3;
        aP0 = A + (size_t)(m0 + r0) * K + c0;
        bP0 = Bt + (size_t)(n0 + r0) * K + c0;
        d0 = o0 >> 1; db = d0;
        const int o1 = 8192 + tid * 16;                   // [8192,16384)
        const int r1 = o1 >> 6;                           // 128..255
        const int c1 = (((o1 >> 4) & 3) ^ ((r1 >> 1) & 3)) << 3;
        aP1 = A + (size_t)(m0 + r1) * K + c1;
        d1 = o1 >> 1;
    }

    f32x4 acc[4][4];
#pragma unroll
    for (int i = 0; i < 4; i++)
#pragma unroll
        for (int j = 0; j < 4; j++) acc[i][j] = (f32x4){0.f, 0.f, 0.f, 0.f};

    u16* const A0 = Abuf[0]; u16* const A1 = Abuf[1]; u16* const A2 = Abuf[2];
    u16* const B0 = Bbuf[0]; u16* const B1 = Bbuf[1]; u16* const B2 = Bbuf[2];

#define GISSUE(WA, WB)                                                      \
    {                                                                       \
        a_copy16(aP0, (WA) + d0); a_copy16(aP1, (WA) + d1);                 \
        a_copy16(bP0, (WB) + db);                                           \
        aP0 += 32; aP1 += 32; bP0 += 32;                                    \
    }

#define KSTEP(RA, RB, WA, WB, DOISS, VMS)                                   \
    {                                                                       \
        asm volatile("s_waitcnt vmcnt(" VMS ")" ::: "memory");              \
        __builtin_amdgcn_s_barrier();                                       \
        __builtin_amdgcn_sched_barrier(0);                                  \
        if (DOISS) GISSUE(WA, WB);                                          \
        __builtin_amdgcn_sched_barrier(0);                                  \
        bf16x8 bfr[4];                                                      \
        _Pragma("unroll")                                                   \
        for (int ni = 0; ni < 4; ni++) {                                    \
            const int row = wc + ni * 16 + lr;                              \
            const int slot = g ^ ((row >> 1) & 3);                          \
            bfr[ni] = *(const bf16x8*)((RB) + row * 32 + slot * 8);         \
        }                                                                   \
        _Pragma("unroll")                                                   \
        for (int mi = 0; mi < 4; mi++) {                                    \
            const int row = wr + mi * 16 + lr;                              \
            const int slot = g ^ ((row >> 1) & 3);                          \
            const bf16x8 af = *(const bf16x8*)((RA) + row * 32 + slot * 8); \
            _Pragma("unroll")                                               \
            for (int ni = 0; ni < 4; ni++)                                  \
                acc[mi][ni] = mfma16(af, bfr[ni], acc[mi][ni]);             \
        }                                                                   \
    }

    // prologue: stage tiles 0 and 1 (6 loads/thread in flight)
    GISSUE(A0, B0);
    GISSUE(A1, B1);

    const int nb = (K >> 5) / 3;   // 4 (K=384) or 16 (K=1536)
    for (int blk = 0; blk < nb - 1; ++blk) {
        KSTEP(A0, B0, A2, B2, 1, "3")
        KSTEP(A1, B1, A0, B0, 1, "3")
        KSTEP(A2, B2, A1, B1, 1, "3")
    }
    // final 3 steps: t = nt-3 (issues nt-1), nt-2, nt-1
    KSTEP(A0, B0, A2, B2, 1, "3")
    KSTEP(A1, B1, A0, B0, 0, "3")
    KSTEP(A2, B2, A1, B1, 0, "0")
#undef KSTEP
#undef GISSUE

    // epilogue
    const int g4 = g << 2;
    float bs[4];
    if (EPI != 0) {
#pragma unroll
        for (int ni = 0; ni < 4; ni++) bs[ni] = bias[n0 + wc + ni * 16 + lr];
    }
#pragma unroll
    for (int mi = 0; mi < 4; mi++) {
#pragma unroll
        for (int r = 0; r < 4; r++) {
            const long m = m0 + wr + mi * 16 + g4 + r;
            long mo = m;
            if (EPI == 1) {  // shifted coords -> original coords (roll back)
                long b = m / HW2;
                int rem = (int)(m % HW2);
                int y = rem / 56 + 3; if (y >= 56) y -= 56;
                int x = rem % 56 + 3; if (x >= 56) x -= 56;
                mo = b * HW2 + y * 56 + x;
            }
            u16* pb = (EPI == 0 || EPI == 2) ? outb + (size_t)m * N + n0 + wc + lr : nullptr;
            float* pf = (EPI == 1 || EPI == 3) ? outf + (size_t)mo * 384 + n0 + wc + lr : nullptr;
            const float* pr = (EPI == 1 || EPI == 3)
                                  ? resid + (size_t)mo * 384 + n0 + wc + lr : nullptr;
#pragma unroll
            for (int ni = 0; ni < 4; ni++) {
                const float v = acc[mi][ni][r];
                if (EPI == 0) {
                    pb[ni * 16] = f2bf(v);
                } else if (EPI == 1 || EPI == 3) {
                    pf[ni * 16] = pr[ni * 16] + v + bs[ni];
                } else {  // fast tanh-GELU: x * sigmoid(2*0.79788..*(x+0.044715x^3))
                    const float gx = v + bs[ni];
                    const float y = 0.7978845608028654f * gx * (1.f + 0.044715f * gx * gx);
                    const float e = __expf(-2.f * y);
                    pb[ni * 16] = f2bf(gx * __builtin_amdgcn_rcpf(1.f + e));
                }
            }
        }
    }
}

// ---------------------------------------------------------------------------
// Windowed attention. One wave per (window, head). qkv rows in shifted
// coords (chunk-local); windows are contiguous 7x7 patches. S in registers;
// softmax via shfl within 16-lane col groups; P,Vt in padded LDS (stride 72).
// ---------------------------------------------------------------------------
__global__ __launch_bounds__(256) void attn_kernel(const u16* __restrict__ qkv,
                                                   const float* __restrict__ tab,
                                                   u16* __restrict__ outa) {
    __shared__ u16 sVt[4][2304];  // [wave][32 d][72 tokens]
    __shared__ u16 sP[4][4608];   // [wave][64 rows][72 cols]
    const int lane = threadIdx.x & 63;
    const int wave = threadIdx.x >> 6;
    const int bid = blockIdx.x;
    const int hg = bid % 3;
    const int win = (bid / 3) & 63;
    const int b = bid / 192;
    const int wy = win >> 3, wx = win & 7;
    const int head = hg * 4 + wave;
    const long wbase = (long)b * HW2 + (long)wy * 392 + wx * 7;  // 392 = 7*56
    const int c = lane & 15, g = lane >> 4;
    const int kk = g << 3;

    // stage V transposed (zero pad cols >=49)
    u16* vt = sVt[wave];
    for (int i = lane; i < 2304; i += 64) vt[i] = 0;
    if (lane < 49) {
        const long mr = wbase + (lane / 7) * 56 + (lane % 7);
        const u16* vr = qkv + mr * 1152 + 768 + head * 32;
#pragma unroll
        for (int u = 0; u < 4; u++) {
            u16x8 vv = *(const u16x8*)(vr + u * 8);
#pragma unroll
            for (int e = 0; e < 8; e++) vt[(u * 8 + e) * 72 + lane] = vv[e];
        }
    }

    // Q (A-operand) and K (B-operand) fragments straight from global
    bf16x8 aq[4], bk[4];
#pragma unroll
    for (int mi = 0; mi < 4; mi++) {
        int t = mi * 16 + c; t = t > 48 ? 48 : t;
        const long mr = wbase + (t / 7) * 56 + (t % 7);
        aq[mi] = *(const bf16x8*)(qkv + mr * 1152 + head * 32 + kk);
    }
#pragma unroll
    for (int ni = 0; ni < 4; ni++) {
        int t = ni * 16 + c; t = t > 48 ? 48 : t;
        const long mr = wbase + (t / 7) * 56 + (t % 7);
        bk[ni] = *(const bf16x8*)(qkv + mr * 1152 + 384 + head * 32 + kk);
    }

    f32x4 sc[4][4];
#pragma unroll
    for (int i = 0; i < 4; i++)
#pragma unroll
        for (int j = 0; j < 4; j++) sc[i][j] = (f32x4){0.f, 0.f, 0.f, 0.f};
#pragma unroll
    for (int mi = 0; mi < 4; mi++)
#pragma unroll
        for (int ni = 0; ni < 4; ni++) sc[mi][ni] = mfma16(aq[mi], bk[ni], sc[mi][ni]);

    // scale + bias + masks (precombined table), in place
    const float* tb = tab + (((wy == 7) ? 1 : 0) | ((wx == 7) ? 2 : 0)) * 2401;
#pragma unroll
    for (int mi = 0; mi < 4; mi++) {
#pragma unroll
        for (int r = 0; r < 4; r++) {
            int i = mi * 16 + (g << 2) + r;
            int ic = i > 48 ? 48 : i;
#pragma unroll
            for (int ni = 0; ni < 4; ni++) {
                int j = ni * 16 + c;
                float sv;
                if (j < 49)
                    sv = sc[mi][ni][r] * 0.17677669529663689f + tb[ic * 49 + j];
                else
                    sv = -3.0e38f;  // pad col -> exp() underflows to 0
                sc[mi][ni][r] = sv;
            }
        }
    }

    // row softmax + write P (bf16) to LDS
    u16* pp = sP[wave];
#pragma unroll
    for (int mi = 0; mi < 4; mi++) {
#pragma unroll
        for (int r = 0; r < 4; r++) {
            float sm = fmaxf(fmaxf(sc[mi][0][r], sc[mi][1][r]),
                             fmaxf(sc[mi][2][r], sc[mi][3][r]));
            sm = fmaxf(sm, __shfl_xor(sm, 1));
            sm = fmaxf(sm, __shfl_xor(sm, 2));
            sm = fmaxf(sm, __shfl_xor(sm, 4));
            sm = fmaxf(sm, __shfl_xor(sm, 8));
            float p0 = __expf(sc[mi][0][r] - sm);
            float p1 = __expf(sc[mi][1][r] - sm);
            float p2 = __expf(sc[mi][2][r] - sm);
            float p3 = __expf(sc[mi][3][r] - sm);
            float ss = p0 + p1 + p2 + p3;
            ss += __shfl_xor(ss, 1);
            ss += __shfl_xor(ss, 2);
            ss += __shfl_xor(ss, 4);
            ss += __shfl_xor(ss, 8);
            const float ri = 1.f / ss;
            const int i = mi * 16 + (g << 2) + r;
            pp[i * 72 + c] = f2bf(p0 * ri);
            pp[i * 72 + 16 + c] = f2bf(p1 * ri);
            pp[i * 72 + 32 + c] = f2bf(p2 * ri);
            pp[i * 72 + 48 + c] = f2bf(p3 * ri);
        }
    }
    __syncthreads();

    // O = P @ V
    f32x4 oc[4][2];
#pragma unroll
    for (int i = 0; i < 4; i++) {
        oc[i][0] = (f32x4){0.f, 0.f, 0.f, 0.f};
        oc[i][1] = (f32x4){0.f, 0.f, 0.f, 0.f};
    }
#pragma unroll
    for (int ks = 0; ks < 2; ks++) {
        bf16x8 bv0 = *(const bf16x8*)(vt + c * 72 + kk + ks * 32);
        bf16x8 bv1 = *(const bf16x8*)(vt + (16 + c) * 72 + kk + ks * 32);
#pragma unroll
        for (int mi = 0; mi < 4; mi++) {
            bf16x8 ap = *(const bf16x8*)(pp + (mi * 16 + c) * 72 + kk + ks * 32);
            oc[mi][0] = mfma16(ap, bv0, oc[mi][0]);
            oc[mi][1] = mfma16(ap, bv1, oc[mi][1]);
        }
    }

    // store O (only valid 49 rows)
#pragma unroll
    for (int mi = 0; mi < 4; mi++) {
#pragma unroll
        for (int r = 0; r < 4; r++) {
            const int i = mi * 16 + (g << 2) + r;
            if (i < 49) {
                const long mr = wbase + (i / 7) * 56 + (i % 7);
                u16* po = outa + mr * 384 + head * 32;
                po[c] = f2bf(oc[mi][0][r]);
                po[16 + c] = f2bf(oc[mi][1][r]);
            }
        }
    }
}

// ---------------------------------------------------------------------------
extern "C" void kernel_launch(void* const* d_in, const int* in_sizes, int n_in,
                              void* d_out, int out_size, void* d_ws, size_t ws_size,
                              hipStream_t stream) {
    (void)in_sizes; (void)n_in; (void)out_size;
    const float* x     = (const float*)d_in[0];
    const float* w_qkv = (const float*)d_in[1];
    const float* pos   = (const float*)d_in[2];
    const float* w_out = (const float*)d_in[3];
    const float* b_out = (const float*)d_in[4];
    const float* ln1g  = (const float*)d_in[5];
    const float* ln1b  = (const float*)d_in[6];
    const float* ln2g  = (const float*)d_in[7];
    const float* ln2b  = (const float*)d_in[8];
    const float* w1    = (const float*)d_in[9];
    const float* b1    = (const float*)d_in[10];
    const float* w2    = (const float*)d_in[11];
    const float* b2    = (const float*)d_in[12];
    float* out = (float*)d_out;
    char* ws = (char*)d_ws;

    // fixed region: bf16 weights + bias tables
    u16* wqkvT  = (u16*)(ws + 0);               //  1152x384 bf16  (884736 B)
    u16* woutT  = (u16*)(ws + 884736);          //   384x384 bf16  (294912 B)
    u16* wm1T   = (u16*)(ws + 1179648);         //  1536x384 bf16  (1179648 B)
    u16* wm2T   = (u16*)(ws + 2359296);         //   384x1536 bf16 (1179648 B)
    float* tab  = (float*)(ws + 3538944);       //  4x49x49 f32    (38416 B)
    const size_t pool0 = 3577856;               //  16-aligned pool start
    const size_t avail = (ws_size > pool0) ? ws_size - pool0 : 0;

    // batch-chunk: CH images need CH*3136*(768 + 2304 + 768) = CH*12,042,240 B
    // CH multiple of 4 so chunk rows are a multiple of 256 (GEMM M-tile).
    int CH = 64;
    while (CH > 4 && (size_t)CH * 12042240ULL > avail) CH >>= 1;
    const int nchunks = 64 / CH;
    u16* bufA = (u16*)(ws + pool0);
    u16* bufB = (u16*)(ws + pool0 + (size_t)CH * 2408448ULL);  // contiguous with bufC
    const int rows = CH * HW2;          // chunk rows (CH%4==0 -> rows%256==0)
    const int tiles = rows >> 8;        // 256-row M-tiles

    // weight prep + tables (small, once per call)
    wtrans<<<1728, 256, 0, stream>>>(w_qkv, wqkvT, 384, 1152);
    wtrans<<<576, 256, 0, stream>>>(w_out, woutT, 384, 384);
    wtrans<<<2304, 256, 0, stream>>>(w1, wm1T, 384, 1536);
    wtrans<<<2304, 256, 0, stream>>>(w2, wm2T, 1536, 384);
    prep_tab<<<38, 256, 0, stream>>>(pos, tab);

    // ---- attention phase, per batch-chunk ----
    for (int c = 0; c < nchunks; ++c) {
        const float* xc = x + (size_t)c * rows * 384;
        float* oc = out + (size_t)c * rows * 384;
        u16* attc = bufB + (size_t)rows * 1152;  // bufC, right after bufB
        ln_kernel<1><<<rows / 4, 256, 0, stream>>>(xc, bufA, ln1g, ln1b);
        gemm_bf16<0><<<tiles * 9, 512, 0, stream>>>(bufA, wqkvT, 1152, 384,
                                                    nullptr, nullptr, nullptr, bufB);
        attn_kernel<<<CH * 192, 256, 0, stream>>>(bufB, tab, attc);
        gemm_bf16<1><<<tiles * 3, 512, 0, stream>>>(attc, woutT, 384, 384,
                                                    b_out, xc, oc, nullptr);
    }

    // ---- MLP phase, per batch-chunk (bufB+bufC span holds h: rows*1536 bf16) ----
    for (int c = 0; c < nchunks; ++c) {
        float* xr = out + (size_t)c * rows * 384;
        ln_kernel<0><<<rows / 4, 256, 0, stream>>>(xr, bufA, ln2g, ln2b);
        gemm_bf16<2><<<tiles * 12, 512, 0, stream>>>(bufA, wm1T, 1536, 384,
                                                     b1, nullptr, nullptr, bufB);
        gemm_bf16<3><<<tiles * 3, 512, 0, stream>>>(bufB, wm2T, 384, 1536,
                                                    b2, xr, xr, nullptr);
    }
}

// Round 10
// 1568.899 us; speedup vs baseline: 1.2495x; 1.2495x over previous
//
#include <hip/hip_runtime.h>
#include <stdint.h>
#include <stddef.h>

// ---------------------------------------------------------------------------
// Swin block, MI355X. bf16 MFMA GEMMs + fused window attention.
// B=64, HW=56, DIM=384, HEADS=12, HEAD_DIM=32, MLP=1536, WS=7, shift=3
// Round 10: R8 GEMM chassis (proven best: BK=64, 2-barrier, 4 waves/SIMD).
// New: bf16 residual x1 in ws (proj->bf16, LN2/MLP2 read bf16) and per-chunk
// full-pipeline execution at CH=16 so the 231MB chunk working set cycles in
// the 256MB Infinity Cache (qkv/h/x1 never round-trip HBM).
// ---------------------------------------------------------------------------

typedef unsigned short u16;
typedef __attribute__((ext_vector_type(8))) short bf16x8;
typedef __attribute__((ext_vector_type(8))) unsigned short u16x8;
typedef __attribute__((ext_vector_type(4))) float f32x4;
typedef __attribute__((ext_vector_type(2))) float f32x2;

#define HW2 3136   // 56*56

__device__ __forceinline__ u16 f2bf(float f) {
    unsigned u = __float_as_uint(f);
    return (u16)((u + 0x7FFFu + ((u >> 16) & 1u)) >> 16);
}

__device__ __forceinline__ float bf2f(u16 u) {
    return __uint_as_float((unsigned)u << 16);
}

__device__ __forceinline__ f32x4 mfma16(bf16x8 a, bf16x8 b, f32x4 c) {
    return __builtin_amdgcn_mfma_f32_16x16x32_bf16(a, b, c, 0, 0, 0);
}

__device__ __forceinline__ void a_copy16(const void* g, void* l) {
    __builtin_amdgcn_global_load_lds((const __attribute__((address_space(1))) void*)g,
                                     (__attribute__((address_space(3))) void*)l, 16, 0, 0);
}

// pair loaders for LN (f32 or bf16 input)
__device__ __forceinline__ f32x2 ld2(const float* p) { return *(const f32x2*)p; }
__device__ __forceinline__ f32x2 ld2(const u16* p) {
    const unsigned u = *(const unsigned*)p;
    f32x2 r;
    r.x = __uint_as_float(u << 16);
    r.y = __uint_as_float(u & 0xffff0000u);
    return r;
}

// ---------------------------------------------------------------------------
// Weight transpose + bf16 convert: w[K][N] -> wt[N][K]
// ---------------------------------------------------------------------------
__global__ __launch_bounds__(256) void wtrans(const float* __restrict__ w,
                                              u16* __restrict__ wt, int K, int N) {
    long tid = (long)blockIdx.x * 256 + threadIdx.x;
    if (tid >= (long)K * N) return;
    int n = (int)(tid / K), k = (int)(tid % K);
    wt[tid] = f2bf(w[(long)k * N + n]);
}

// ---------------------------------------------------------------------------
// bias tables: tab[4][49][49] = pos_emb[rel] (+ul mask)(+lr mask)
// ---------------------------------------------------------------------------
__global__ __launch_bounds__(256) void prep_tab(const float* __restrict__ pe,
                                                float* __restrict__ tab) {
    int tid = blockIdx.x * 256 + threadIdx.x;
    if (tid >= 4 * 2401) return;
    int cb = tid / 2401, rem = tid % 2401;
    int i = rem / 49, j = rem % 49;
    int ix = i % 7, jx = j % 7;
    int iy = i / 7, jy = j / 7;
    float v = pe[(jy - iy + 6) * 13 + (jx - ix + 6)];
    if ((cb & 1) && ((i >= 28) != (j >= 28))) v += -1e9f;  // ul (bottom window row)
    if ((cb & 2) && ((ix >= 4) != (jx >= 4))) v += -1e9f;  // lr (right window col)
    tab[tid] = v;
}

// ---------------------------------------------------------------------------
// LayerNorm over 384, one wave per token (rows chunk-local). SHIFT=1: write
// rows in cyclically shifted order so attention sees contiguous windows.
// TIN: float (x input) or u16 (bf16 residual stream).
// ---------------------------------------------------------------------------
template <int SHIFT, typename TIN>
__global__ __launch_bounds__(256) void ln_kernel(const TIN* __restrict__ in,
                                                 u16* __restrict__ out,
                                                 const float* __restrict__ gw,
                                                 const float* __restrict__ bw) {
    const int lane = threadIdx.x & 63;
    const int wave = threadIdx.x >> 6;
    const long t = (long)blockIdx.x * 4 + wave;
    const TIN* row = in + t * 384;
    f32x2 v0 = ld2(row + lane * 2);
    f32x2 v1 = ld2(row + 128 + lane * 2);
    f32x2 v2 = ld2(row + 256 + lane * 2);
    float s = v0.x + v0.y + v1.x + v1.y + v2.x + v2.y;
    float q = v0.x * v0.x + v0.y * v0.y + v1.x * v1.x + v1.y * v1.y + v2.x * v2.x + v2.y * v2.y;
#pragma unroll
    for (int m = 1; m < 64; m <<= 1) {
        s += __shfl_xor(s, m);
        q += __shfl_xor(q, m);
    }
    const float mean = s * (1.f / 384.f);
    const float rstd = rsqrtf(q * (1.f / 384.f) - mean * mean + 1e-5f);
    long orow = t;
    if (SHIFT) {
        long b = t / HW2;
        int rem = (int)(t % HW2);
        int y = rem / 56 - 3; if (y < 0) y += 56;
        int x = rem % 56 - 3; if (x < 0) x += 56;
        orow = b * HW2 + y * 56 + x;
    }
    u16* po = out + orow * 384;
#pragma unroll
    for (int p = 0; p < 3; p++) {
        f32x2 vv = (p == 0) ? v0 : ((p == 1) ? v1 : v2);
        f32x2 gg = *(const f32x2*)(gw + p * 128 + lane * 2);
        f32x2 bb = *(const f32x2*)(bw + p * 128 + lane * 2);
        float a0 = (vv.x - mean) * rstd * gg.x + bb.x;
        float a1 = (vv.y - mean) * rstd * gg.y + bb.y;
        unsigned pk = (unsigned)f2bf(a0) | ((unsigned)f2bf(a1) << 16);
        *(unsigned*)(po + p * 128 + lane * 2) = pk;
    }
}

// ---------------------------------------------------------------------------
// bf16 GEMM: 128x128 tile, BK=64, 4 waves 2x2, 16x16x32 MFMA. R8 chassis:
// simple 2-barrier K-loop, global_load_lds(16B), linear LDS dest +
// pre-swizzled global source; reads use the same XOR (slot ^= row&7).
// __launch_bounds__(256,4): 128 unified regs -> 4 waves/SIMD.
// A[M][K], Bt[N][K].
// EPI: 0 = bf16 store (QKV)
//      1 = proj: bf16 out = f2bf(f32resid + v + bias), rows un-shifted
//      2 = +bias fast-GELU bf16 (MLP1)
//      3 = f32 out = bf16resid + v + bias (MLP2, final)
// Grids XCD-swizzled when gridDim%8==0.
// ---------------------------------------------------------------------------
template <int EPI>
__global__ __launch_bounds__(256, 4) void gemm_bf16(const u16* __restrict__ A,
                                                    const u16* __restrict__ Bt,
                                                    int N, int K,
                                                    const float* __restrict__ bias,
                                                    const void* residv,
                                                    float* outf, u16* outb) {
    __shared__ u16 Abuf[8192];   // 128 rows x 64 cols
    __shared__ u16 Bbuf[8192];
    int bid = blockIdx.x;
    if ((gridDim.x & 7) == 0) {     // XCD-aware swizzle (bijective, %8==0)
        const int cpx = gridDim.x >> 3;
        bid = (bid & 7) * cpx + (bid >> 3);
    }
    const int ntiles = N >> 7;
    const long m0 = (long)(bid / ntiles) << 7;
    const int n0 = (bid % ntiles) << 7;
    const int lane = threadIdx.x & 63;
    const int wave = threadIdx.x >> 6;
    const int wr = (wave >> 1) << 6;
    const int wc = (wave & 1) << 6;
    const int lr = lane & 15;
    const int g  = lane >> 4;

    // staging: 4 segs/thread/matrix; LDS dest linear, source slot-swizzled
    const u16* aP0; const u16* aP1; const u16* aP2; const u16* aP3;
    const u16* bP0; const u16* bP1; const u16* bP2; const u16* bP3;
    int d0, d1, d2, d3;
    {
#define STAGE_INIT(j, aP, bP, dd)                                          \
        {                                                                  \
            const int o = (((j << 2) + wave) << 10) + lane * 16;           \
            const int row = o >> 7;                                        \
            const int slot = (o >> 4) & 7;                                 \
            const int ce = ((slot ^ (row & 7)) << 3);                      \
            aP = A + (size_t)(m0 + row) * K + ce;                          \
            bP = Bt + (size_t)(n0 + row) * K + ce;                         \
            dd = o >> 1;                                                   \
        }
        STAGE_INIT(0, aP0, bP0, d0)
        STAGE_INIT(1, aP1, bP1, d1)
        STAGE_INIT(2, aP2, bP2, d2)
        STAGE_INIT(3, aP3, bP3, d3)
#undef STAGE_INIT
    }

    f32x4 acc[4][4];
#pragma unroll
    for (int i = 0; i < 4; i++)
#pragma unroll
        for (int j = 0; j < 4; j++) acc[i][j] = (f32x4){0.f, 0.f, 0.f, 0.f};

    for (int k0 = 0; k0 < K; k0 += 64) {
        __syncthreads();
        a_copy16(aP0, Abuf + d0); a_copy16(bP0, Bbuf + d0); aP0 += 64; bP0 += 64;
        a_copy16(aP1, Abuf + d1); a_copy16(bP1, Bbuf + d1); aP1 += 64; bP1 += 64;
        a_copy16(aP2, Abuf + d2); a_copy16(bP2, Bbuf + d2); aP2 += 64; bP2 += 64;
        a_copy16(aP3, Abuf + d3); a_copy16(bP3, Bbuf + d3); aP3 += 64; bP3 += 64;
        __syncthreads();
#pragma unroll
        for (int t = 0; t < 2; t++) {
            bf16x8 bfr[4];
#pragma unroll
            for (int ni = 0; ni < 4; ni++) {
                const int row = wc + ni * 16 + lr;
                const int slot = ((t << 2) + g) ^ (row & 7);
                bfr[ni] = *(const bf16x8*)(Bbuf + row * 64 + slot * 8);
            }
#pragma unroll
            for (int mi = 0; mi < 4; mi++) {
                const int row = wr + mi * 16 + lr;
                const int slot = ((t << 2) + g) ^ (row & 7);
                const bf16x8 af = *(const bf16x8*)(Abuf + row * 64 + slot * 8);
#pragma unroll
                for (int ni = 0; ni < 4; ni++)
                    acc[mi][ni] = mfma16(af, bfr[ni], acc[mi][ni]);
            }
        }
    }

    // epilogue
    const float* residf = (const float*)residv;  // EPI1
    const u16*  residb  = (const u16*)residv;    // EPI3
    const int g4 = g << 2;
    float bs[4];
    if (EPI != 0) {
#pragma unroll
        for (int ni = 0; ni < 4; ni++) bs[ni] = bias[n0 + wc + ni * 16 + lr];
    }
#pragma unroll
    for (int mi = 0; mi < 4; mi++) {
#pragma unroll
        for (int r = 0; r < 4; r++) {
            const long m = m0 + wr + mi * 16 + g4 + r;
            long mo = m;
            if (EPI == 1) {  // shifted coords -> original coords (roll back)
                long b = m / HW2;
                int rem = (int)(m % HW2);
                int y = rem / 56 + 3; if (y >= 56) y -= 56;
                int x = rem % 56 + 3; if (x >= 56) x -= 56;
                mo = b * HW2 + y * 56 + x;
            }
#pragma unroll
            for (int ni = 0; ni < 4; ni++) {
                const float v = acc[mi][ni][r];
                const int n = n0 + wc + ni * 16 + lr;
                if (EPI == 0) {
                    outb[(size_t)m * N + n] = f2bf(v);
                } else if (EPI == 1) {
                    const size_t o = (size_t)mo * 384 + n;
                    outb[o] = f2bf(residf[o] + v + bs[ni]);
                } else if (EPI == 2) {
                    const float gx = v + bs[ni];
                    const float y = 0.7978845608028654f * gx * (1.f + 0.044715f * gx * gx);
                    const float e = __expf(-2.f * y);
                    outb[(size_t)m * N + n] = f2bf(gx * __builtin_amdgcn_rcpf(1.f + e));
                } else {
                    const size_t o = (size_t)m * 384 + n;
                    outf[o] = bf2f(residb[o]) + v + bs[ni];
                }
            }
        }
    }
}

// ---------------------------------------------------------------------------
// Windowed attention. One wave per (window, head). qkv rows in shifted
// coords (chunk-local); windows are contiguous 7x7 patches. S in registers;
// softmax via shfl within 16-lane col groups; P,Vt in padded LDS (stride 72).
// ---------------------------------------------------------------------------
__global__ __launch_bounds__(256) void attn_kernel(const u16* __restrict__ qkv,
                                                   const float* __restrict__ tab,
                                                   u16* __restrict__ outa) {
    __shared__ u16 sVt[4][2304];  // [wave][32 d][72 tokens]
    __shared__ u16 sP[4][4608];   // [wave][64 rows][72 cols]
    const int lane = threadIdx.x & 63;
    const int wave = threadIdx.x >> 6;
    const int bid = blockIdx.x;
    const int hg = bid % 3;
    const int win = (bid / 3) & 63;
    const int b = bid / 192;
    const int wy = win >> 3, wx = win & 7;
    const int head = hg * 4 + wave;
    const long wbase = (long)b * HW2 + (long)wy * 392 + wx * 7;  // 392 = 7*56
    const int c = lane & 15, g = lane >> 4;
    const int kk = g << 3;

    // stage V transposed (zero pad cols >=49)
    u16* vt = sVt[wave];
    for (int i = lane; i < 2304; i += 64) vt[i] = 0;
    if (lane < 49) {
        const long mr = wbase + (lane / 7) * 56 + (lane % 7);
        const u16* vr = qkv + mr * 1152 + 768 + head * 32;
#pragma unroll
        for (int u = 0; u < 4; u++) {
            u16x8 vv = *(const u16x8*)(vr + u * 8);
#pragma unroll
            for (int e = 0; e < 8; e++) vt[(u * 8 + e) * 72 + lane] = vv[e];
        }
    }

    // Q (A-operand) and K (B-operand) fragments straight from global
    bf16x8 aq[4], bk[4];
#pragma unroll
    for (int mi = 0; mi < 4; mi++) {
        int t = mi * 16 + c; t = t > 48 ? 48 : t;
        const long mr = wbase + (t / 7) * 56 + (t % 7);
        aq[mi] = *(const bf16x8*)(qkv + mr * 1152 + head * 32 + kk);
    }
#pragma unroll
    for (int ni = 0; ni < 4; ni++) {
        int t = ni * 16 + c; t = t > 48 ? 48 : t;
        const long mr = wbase + (t / 7) * 56 + (t % 7);
        bk[ni] = *(const bf16x8*)(qkv + mr * 1152 + 384 + head * 32 + kk);
    }

    f32x4 sc[4][4];
#pragma unroll
    for (int i = 0; i < 4; i++)
#pragma unroll
        for (int j = 0; j < 4; j++) sc[i][j] = (f32x4){0.f, 0.f, 0.f, 0.f};
#pragma unroll
    for (int mi = 0; mi < 4; mi++)
#pragma unroll
        for (int ni = 0; ni < 4; ni++) sc[mi][ni] = mfma16(aq[mi], bk[ni], sc[mi][ni]);

    // scale + bias + masks (precombined table), in place
    const float* tb = tab + (((wy == 7) ? 1 : 0) | ((wx == 7) ? 2 : 0)) * 2401;
#pragma unroll
    for (int mi = 0; mi < 4; mi++) {
#pragma unroll
        for (int r = 0; r < 4; r++) {
            int i = mi * 16 + (g << 2) + r;
            int ic = i > 48 ? 48 : i;
#pragma unroll
            for (int ni = 0; ni < 4; ni++) {
                int j = ni * 16 + c;
                float sv;
                if (j < 49)
                    sv = sc[mi][ni][r] * 0.17677669529663689f + tb[ic * 49 + j];
                else
                    sv = -3.0e38f;  // pad col -> exp() underflows to 0
                sc[mi][ni][r] = sv;
            }
        }
    }

    // row softmax + write P (bf16) to LDS
    u16* pp = sP[wave];
#pragma unroll
    for (int mi = 0; mi < 4; mi++) {
#pragma unroll
        for (int r = 0; r < 4; r++) {
            float sm = fmaxf(fmaxf(sc[mi][0][r], sc[mi][1][r]),
                             fmaxf(sc[mi][2][r], sc[mi][3][r]));
            sm = fmaxf(sm, __shfl_xor(sm, 1));
            sm = fmaxf(sm, __shfl_xor(sm, 2));
            sm = fmaxf(sm, __shfl_xor(sm, 4));
            sm = fmaxf(sm, __shfl_xor(sm, 8));
            float p0 = __expf(sc[mi][0][r] - sm);
            float p1 = __expf(sc[mi][1][r] - sm);
            float p2 = __expf(sc[mi][2][r] - sm);
            float p3 = __expf(sc[mi][3][r] - sm);
            float ss = p0 + p1 + p2 + p3;
            ss += __shfl_xor(ss, 1);
            ss += __shfl_xor(ss, 2);
            ss += __shfl_xor(ss, 4);
            ss += __shfl_xor(ss, 8);
            const float ri = 1.f / ss;
            const int i = mi * 16 + (g << 2) + r;
            pp[i * 72 + c] = f2bf(p0 * ri);
            pp[i * 72 + 16 + c] = f2bf(p1 * ri);
            pp[i * 72 + 32 + c] = f2bf(p2 * ri);
            pp[i * 72 + 48 + c] = f2bf(p3 * ri);
        }
    }
    __syncthreads();

    // O = P @ V
    f32x4 oc[4][2];
#pragma unroll
    for (int i = 0; i < 4; i++) {
        oc[i][0] = (f32x4){0.f, 0.f, 0.f, 0.f};
        oc[i][1] = (f32x4){0.f, 0.f, 0.f, 0.f};
    }
#pragma unroll
    for (int ks = 0; ks < 2; ks++) {
        bf16x8 bv0 = *(const bf16x8*)(vt + c * 72 + kk + ks * 32);
        bf16x8 bv1 = *(const bf16x8*)(vt + (16 + c) * 72 + kk + ks * 32);
#pragma unroll
        for (int mi = 0; mi < 4; mi++) {
            bf16x8 ap = *(const bf16x8*)(pp + (mi * 16 + c) * 72 + kk + ks * 32);
            oc[mi][0] = mfma16(ap, bv0, oc[mi][0]);
            oc[mi][1] = mfma16(ap, bv1, oc[mi][1]);
        }
    }

    // store O (only valid 49 rows)
#pragma unroll
    for (int mi = 0; mi < 4; mi++) {
#pragma unroll
        for (int r = 0; r < 4; r++) {
            const int i = mi * 16 + (g << 2) + r;
            if (i < 49) {
                const long mr = wbase + (i / 7) * 56 + (i % 7);
                u16* po = outa + mr * 384 + head * 32;
                po[c] = f2bf(oc[mi][0][r]);
                po[16 + c] = f2bf(oc[mi][1][r]);
            }
        }
    }
}

// ---------------------------------------------------------------------------
extern "C" void kernel_launch(void* const* d_in, const int* in_sizes, int n_in,
                              void* d_out, int out_size, void* d_ws, size_t ws_size,
                              hipStream_t stream) {
    (void)in_sizes; (void)n_in; (void)out_size;
    const float* x     = (const float*)d_in[0];
    const float* w_qkv = (const float*)d_in[1];
    const float* pos   = (const float*)d_in[2];
    const float* w_out = (const float*)d_in[3];
    const float* b_out = (const float*)d_in[4];
    const float* ln1g  = (const float*)d_in[5];
    const float* ln1b  = (const float*)d_in[6];
    const float* ln2g  = (const float*)d_in[7];
    const float* ln2b  = (const float*)d_in[8];
    const float* w1    = (const float*)d_in[9];
    const float* b1    = (const float*)d_in[10];
    const float* w2    = (const float*)d_in[11];
    const float* b2    = (const float*)d_in[12];
    float* out = (float*)d_out;
    char* ws = (char*)d_ws;

    // fixed region: bf16 weights + bias tables
    u16* wqkvT  = (u16*)(ws + 0);               //  1152x384 bf16  (884736 B)
    u16* woutT  = (u16*)(ws + 884736);          //   384x384 bf16  (294912 B)
    u16* wm1T   = (u16*)(ws + 1179648);         //  1536x384 bf16  (1179648 B)
    u16* wm2T   = (u16*)(ws + 2359296);         //   384x1536 bf16 (1179648 B)
    float* tab  = (float*)(ws + 3538944);       //  4x49x49 f32    (38416 B)
    const size_t pool0 = 3577856;               //  16-aligned pool start
    const size_t avail = (ws_size > pool0) ? ws_size - pool0 : 0;

    // batch-chunk: per-row bytes = bufA 768 + bufB 2304 + bufC 768 + bufD 768
    // = 4608; CH=16 keeps the chunk working set (~231MB) inside the 256MB L3.
    int CH = 16;
    while (CH > 2 && (size_t)CH * 3136 * 4608ULL > avail) CH >>= 1;
    const int nchunks = 64 / CH;
    const int rows = CH * HW2;          // chunk rows (CH even -> rows%128==0)
    const int tiles = rows >> 7;
    u16* bufA = (u16*)(ws + pool0);                               // ln out (768B/row)
    u16* bufB = bufA + (size_t)rows * 384;                        // qkv / h head (2304B/row)
    u16* bufC = bufB + (size_t)rows * 1152;                       // attn / h tail (768B/row)
    u16* bufD = bufC + (size_t)rows * 384;                        // x1 residual bf16 (768B/row)

    // weight prep + tables (small, once per call)
    wtrans<<<1728, 256, 0, stream>>>(w_qkv, wqkvT, 384, 1152);
    wtrans<<<576, 256, 0, stream>>>(w_out, woutT, 384, 384);
    wtrans<<<2304, 256, 0, stream>>>(w1, wm1T, 384, 1536);
    wtrans<<<2304, 256, 0, stream>>>(w2, wm2T, 1536, 384);
    prep_tab<<<38, 256, 0, stream>>>(pos, tab);

    // ---- full block pipeline per batch-chunk (chunk set stays L3-hot) ----
    for (int c = 0; c < nchunks; ++c) {
        const float* xc = x + (size_t)c * rows * 384;
        float* oc = out + (size_t)c * rows * 384;
        // LN1, rows written in shifted order
        ln_kernel<1, float><<<rows / 4, 256, 0, stream>>>(xc, bufA, ln1g, ln1b);
        // QKV gemm: [rows,384]x[384,1152] -> bufB
        gemm_bf16<0><<<tiles * 9, 256, 0, stream>>>(bufA, wqkvT, 1152, 384,
                                                    nullptr, nullptr, nullptr, bufB);
        // window attention: bufB -> bufC
        attn_kernel<<<CH * 192, 256, 0, stream>>>(bufB, tab, bufC);
        // out proj: bf16 x1 = x + attn@Wout + b, rows un-shifted -> bufD
        gemm_bf16<1><<<tiles * 3, 256, 0, stream>>>(bufC, woutT, 384, 384,
                                                    b_out, xc, nullptr, bufD);
        // LN2 on bf16 residual stream
        ln_kernel<0, u16><<<rows / 4, 256, 0, stream>>>(bufD, bufA, ln2g, ln2b);
        // MLP1 + GELU: [rows,384]x[384,1536] -> bufB..C (h, bf16)
        gemm_bf16<2><<<tiles * 12, 256, 0, stream>>>(bufA, wm1T, 1536, 384,
                                                     b1, nullptr, nullptr, bufB);
        // MLP2 + bias + bf16 residual -> final f32 out
        gemm_bf16<3><<<tiles * 3, 256, 0, stream>>>(bufB, wm2T, 384, 1536,
                                                    b2, bufD, oc, nullptr);
    }
}